// Round 1
// 178.475 us; speedup vs baseline: 1.1235x; 1.1235x over previous
//
#include <hip/hip_runtime.h>
#include <math.h>

#define NB 32
#define NA 5
#define NC 80
#define NH 38
#define NW 38
#define MAXT 50
#define CELLS (NH * NW)   /* 1444 */
#define CH (5 + NC)       /* 85 */
#define NSLICE 29         /* 29*256 = 7424 >= NA*CELLS = 7220: one cell per thread */
#define THREADS 256
#define NWAVES (THREADS / 64)

/* workspace layout (float indices). Total = 14432 floats = 57728 B. */
#define WS_BOX  0                         /* float4 [NB][MAXT]  : x1,y1,x2,y2      */
#define WS_THR  (NB * MAXT * 4)           /* float  [NB][MAXT]  : 0.375*area (3e38 if invalid) */
#define WS_CORR (WS_THR + NB * MAXT)      /* float  [NB]        : matched-cell loss correction */
#define WS_TGTI (WS_CORR + NB)            /* int    [NB][MAXT][4]: winner, cls_off, cls, pad   */

__device__ __forceinline__ float sigmoidf_(float v) {
    return 1.0f / (1.0f + expf(-v));
}

__device__ __forceinline__ float bbox_iou_(float ax, float ay, float aw, float ah,
                                           float bx, float by, float bw, float bh) {
    float mx = fminf(ax - aw * 0.5f, bx - bw * 0.5f);
    float Mx = fmaxf(ax + aw * 0.5f, bx + bw * 0.5f);
    float my = fminf(ay - ah * 0.5f, by - bh * 0.5f);
    float My = fmaxf(ay + ah * 0.5f, by + bh * 0.5f);
    float cw = aw + bw - (Mx - mx);
    float ch = ah + bh - (My - my);
    float inter = (cw > 0.0f && ch > 0.0f) ? cw * ch : 0.0f;
    float uni = aw * ah + bw * bh - inter;
    return inter / fmaxf(uni, 1e-12f);
}

__device__ __constant__ float c_anchors[10] = {
    1.3221f, 1.73145f, 3.19275f, 4.00944f, 5.05587f,
    8.09892f, 9.47112f, 4.84053f, 11.2364f, 10.0071f};

// ---------------------------------------------------------------------------
// Prep kernel: one block (one wave) per batch. Builds the 50 GT records once
// (instead of once per main block), decides winners, computes the per-winner
// matched-cell correction:
//   corr = [matched coord+conf loss] - [uniform unmatched formula at that cell]
// so the main kernel's per-cell loop needs no matched-cell handling at all.
// Also zeroes the scalar loss (replaces the old zero_out kernel).
// ---------------------------------------------------------------------------
__global__ __launch_bounds__(64) void region_prep(const float* __restrict__ out,
                                                  const float* __restrict__ tgt,
                                                  float* __restrict__ ws,
                                                  float* __restrict__ loss) {
    const int b = blockIdx.x;
    const int t = threadIdx.x;          // 0..63, records live in 0..49
    __shared__ float4 s_box[MAXT];
    __shared__ float  s_thr[MAXT];
    __shared__ int    s_key[64];

    float t0 = 0.f, t1 = 0.f, gx = 0.f, gy = 0.f, gw = 0.f, gh = 0.f;
    const bool isrec = (t < MAXT);
    if (isrec) {
        const float* tp = tgt + (long)b * (MAXT * 5) + t * 5;
        t0 = tp[0];
        t1 = tp[1];
        gx = t1 * NW;
        gy = tp[2] * NH;
        gw = tp[3] * NW;
        gh = tp[4] * NH;
    }
    // valid = cumprod(t1 != 0): all earlier slots (and self) nonzero.
    unsigned long long nz = __ballot(isrec && (t1 != 0.0f));
    bool valid = isrec && (((~nz) & ((2ULL << t) - 1ULL)) == 0ULL);

    // best anchor (first max wins, matching argmax)
    int bn = 0;
    float best = -1.0f;
    for (int a = 0; a < NA; ++a) {
        float aw = c_anchors[2 * a], ah = c_anchors[2 * a + 1];
        float inter = fminf(gw, aw) * fminf(gh, ah);
        float uni = gw * gh + aw * ah - inter;
        float iou = inter / fmaxf(uni, 1e-12f);
        if (iou > best) { best = iou; bn = a; }
    }
    int gi = (int)floorf(gx); gi = gi < 0 ? 0 : (gi > NW - 1 ? NW - 1 : gi);
    int gj = (int)floorf(gy); gj = gj < 0 ? 0 : (gj > NH - 1 ? NH - 1 : gj);
    int key = valid ? (bn * CELLS + gj * NW + gi) : -1;
    s_key[t] = key;

    float4 box;
    float thr;
    if (valid) {
        box.x = gx - gw * 0.5f; box.y = gy - gh * 0.5f;
        box.z = gx + gw * 0.5f; box.w = gy + gh * 0.5f;
        thr = 0.375f * (gw * gh);
    } else {
        // degenerate: zero-overlap box + impossible threshold -> never "hit"
        box.x = box.y = box.z = box.w = 0.0f;
        thr = 3e38f;
    }
    if (isrec) { s_box[t] = box; s_thr[t] = thr; }
    __syncthreads();

    // winner = valid and not overwritten by a later slot with the same key
    bool winner = valid;
    if (winner) {
        for (int u = t + 1; u < MAXT; ++u)
            if (s_key[u] == key) { winner = false; break; }
    }

    float corr = 0.0f;
    if (winner) {
        float aw = c_anchors[2 * bn], ah = c_anchors[2 * bn + 1];
        long base = (((long)(b * NA + bn)) * CH) * CELLS + gj * NW + gi;
        float xr = out[base];
        float yr = out[base + CELLS];
        float wr = out[base + 2 * CELLS];
        float hr = out[base + 3 * CELLS];
        float cr = out[base + 4 * CELLS];
        float sx = sigmoidf_(xr), sy = sigmoidf_(yr), sc = sigmoidf_(cr);
        float px = sx + (float)gi, py = sy + (float)gj;
        float pw = expf(wr) * aw, ph = expf(hr) * ah;
        float iou_gt = bbox_iou_(gx, gy, gw, gh, px, py, pw, ph);

        // hit at this cell — EXACTLY the same expression sequence as the main
        // kernel's inner loop (no fp-contraction opportunities -> bit-identical)
        float px1 = px - pw * 0.5f, px2 = px + pw * 0.5f;
        float py1 = py - ph * 0.5f, py2 = py + ph * 0.5f;
        float pthr = 0.375f * (pw * ph);
        bool hit = false;
        for (int u = 0; u < MAXT; ++u) {
            float4 rb = s_box[u];
            float ow = fminf(px2, rb.z) - fmaxf(px1, rb.x);
            float oh = fminf(py2, rb.w) - fmaxf(py1, rb.y);
            ow = fmaxf(ow, 0.0f);
            oh = fmaxf(oh, 0.0f);
            hit = hit | (ow * oh > pthr + s_thr[u]);
        }
        float h01 = hit ? 0.0f : 1.0f;

        float txv = gx - (float)gi, tyv = gy - (float)gj;
        float twv = logf(fmaxf(gw, 1e-12f) / aw);
        float thv = logf(fmaxf(gh, 1e-12f) / ah);
        float dsc = sc - iou_gt;
        corr = 0.5f * ((sx - txv) * (sx - txv) - (sx - 0.5f) * (sx - 0.5f)
                     + (sy - tyv) * (sy - tyv) - (sy - 0.5f) * (sy - 0.5f)
                     + (wr - twv) * (wr - twv) - wr * wr
                     + (hr - thv) * (hr - thv) - hr * hr)
             + 0.5f * (5.0f * dsc * dsc - h01 * sc * sc);
    }

    if (isrec) {
        ((float4*)(ws + WS_BOX))[b * MAXT + t] = box;
        ws[WS_THR + b * MAXT + t] = thr;
        int cls = (int)t0; cls = cls < 0 ? 0 : (cls > NC - 1 ? NC - 1 : cls);
        int* ti = (int*)ws + WS_TGTI + (b * MAXT + t) * 4;
        ti[0] = winner ? 1 : 0;
        ti[1] = (bn * CH + 5) * CELLS + gj * NW + gi;   // class-channel base offset
        ti[2] = cls;
        ti[3] = 0;
    }
    for (int off = 32; off > 0; off >>= 1) corr += __shfl_down(corr, off);
    if (t == 0) {
        ws[WS_CORR + b] = corr;
        if (b == 0) loss[0] = 0.0f;
    }
}

// ---------------------------------------------------------------------------
// Main kernel: grid (NSLICE, NB) x 256. One anchor-cell per thread, fully
// uniform Phase B: record boxes/thresholds come from the workspace via
// wave-uniform (scalar) loads; the only per-record cost is ~11 VALU ops, no
// division, no LDS, no key compare. Class loss (Phase C) per winner record,
// one wave each. One atomicAdd per block.
// ---------------------------------------------------------------------------
__global__ __launch_bounds__(THREADS) void region_main(const float* __restrict__ out,
                                                       const float* __restrict__ ws,
                                                       float* __restrict__ loss) {
    const int bx = blockIdx.x;
    const int b = blockIdx.y;
    const int tid = threadIdx.x;
    const int wid = tid >> 6;
    const int lane = tid & 63;
    __shared__ float s_wpart[NWAVES];

    const int idx0 = bx * THREADS + tid;
    int idx = idx0 < NA * CELLS ? idx0 : NA * CELLS - 1;  // clamp: keep control flow uniform
    const int a = idx / CELLS;
    const int r = idx - a * CELLS;
    const int j = r / NW;
    const int i = r - j * NW;

    const long base = (((long)(b * NA + a)) * CH) * CELLS + r;
    const float xr = out[base];
    const float yr = out[base + CELLS];
    const float wr = out[base + 2 * CELLS];
    const float hr = out[base + 3 * CELLS];
    const float cr = out[base + 4 * CELLS];

    const float sx = sigmoidf_(xr), sy = sigmoidf_(yr), sc = sigmoidf_(cr);
    const float px = sx + (float)i, py = sy + (float)j;
    const float pw = expf(wr) * c_anchors[2 * a];
    const float ph = expf(hr) * c_anchors[2 * a + 1];
    const float px1 = px - pw * 0.5f, px2 = px + pw * 0.5f;
    const float py1 = py - ph * 0.5f, py2 = py + ph * 0.5f;
    const float pthr = 0.375f * (pw * ph);

    const float* sbox = ws + WS_BOX + b * (MAXT * 4);   // wave-uniform addresses -> s_load
    const float* sthr = ws + WS_THR + b * MAXT;
    bool hit = false;
    #pragma unroll
    for (int u = 0; u < MAXT; ++u) {
        float rx = sbox[u * 4 + 0];
        float ry = sbox[u * 4 + 1];
        float rz = sbox[u * 4 + 2];
        float rw = sbox[u * 4 + 3];
        float ow = fminf(px2, rz) - fmaxf(px1, rx);
        float oh = fminf(py2, rw) - fmaxf(py1, ry);
        ow = fmaxf(ow, 0.0f);
        oh = fmaxf(oh, 0.0f);
        hit = hit | (ow * oh > pthr + sthr[u]);   // iou>0.6 <=> inter>0.375*(pa+ga)
    }
    float dx = sx - 0.5f, dy = sy - 0.5f;
    float cellsum = 0.5f * (dx * dx + dy * dy + wr * wr + hr * hr)
                  + (hit ? 0.0f : 0.5f * sc * sc);
    if (idx0 >= NA * CELLS) cellsum = 0.0f;

    // ---- Phase C: class loss, one wave per winner record ----
    float closs = 0.0f;
    const int gwave = __builtin_amdgcn_readfirstlane(bx * NWAVES + wid);  // 0..115
    if (gwave < MAXT) {
        const int* ti = (const int*)ws + WS_TGTI + (b * MAXT + gwave) * 4;
        if (ti[0]) {
            const float* cp = out + (long)b * (NA * CH * CELLS) + ti[1];
            float v0 = cp[(long)lane * CELLS];                          // classes 0..63
            float v1 = (lane < NC - 64) ? cp[(long)(64 + lane) * CELLS] : -INFINITY;
            float m = fmaxf(v0, v1);
            for (int off = 32; off > 0; off >>= 1)
                m = fmaxf(m, __shfl_down(m, off));
            m = __shfl(m, 0);
            float e = expf(v0 - m) + ((lane < NC - 64) ? expf(v1 - m) : 0.0f);
            for (int off = 32; off > 0; off >>= 1)
                e += __shfl_down(e, off);
            if (lane == 0) closs = m + logf(e) - cp[(long)ti[2] * CELLS];
        }
    }
    // matched-cell corrections (one block per batch adds them)
    if (bx == 0 && tid == 0) closs += ws[WS_CORR + b];

    // ---- Reduction: wave shuffle + cross-wave LDS, one atomic per block ----
    float v = cellsum;
    for (int off = 32; off > 0; off >>= 1) v += __shfl_down(v, off);
    if (lane == 0) s_wpart[wid] = v + closs;
    __syncthreads();
    if (tid == 0) {
        float s = 0.0f;
        for (int w = 0; w < NWAVES; ++w) s += s_wpart[w];
        atomicAdd(loss, s);
    }
}

extern "C" void kernel_launch(void* const* d_in, const int* in_sizes, int n_in,
                              void* d_out, int out_size, void* d_ws, size_t ws_size,
                              hipStream_t stream) {
    const float* output = (const float*)d_in[0];
    const float* target = (const float*)d_in[1];
    // d_in[2] = features: unused by the reference.
    float* loss = (float*)d_out;
    float* ws = (float*)d_ws;   // needs 57728 B

    region_prep<<<NB, 64, 0, stream>>>(output, target, ws, loss);
    dim3 grid(NSLICE, NB);
    region_main<<<grid, THREADS, 0, stream>>>(output, ws, loss);
}